// Round 7
// baseline (44.328 us; speedup 1.0000x reference)
//
#include <hip/hip_runtime.h>

#define IMG_H 512
#define IMG_W 512
#define NB    8
#define TILE  32
#define LROWS 34            // owner rows 0..31 + 2 halo rows below
#define LCOLS 36            // owner col j -> lds col j+2 (halo +-2)
#define NBLK  (NB * (IMG_H / TILE) * (IMG_W / TILE))   // 2048
#define INV_N_MEAN (1.0f / 16777216.0f)   // 1 / (B * 8 dirs * H * W)
#define LOG2E 1.44269504f
#define LN2   0.69314718f

__device__ __forceinline__ float frcp(float x){ return __builtin_amdgcn_rcpf(x); }
__device__ __forceinline__ float fexp2(float x){ return __builtin_amdgcn_exp2f(x); }
__device__ __forceinline__ float flog2(float x){ return __builtin_amdgcn_logf(x); }

// Per-pixel pack {s, mw, e', nw}:
//   s  = sigmoid(c_map)
//   mw = (t ? -0.6 : -1.4) * log(sel+1e-4), sel = t ? s : 1-s   (eq-pair num, K=1 weight)
//   e' = (t ? -1 : +1) * exp(-s);  e' == 0  => OOB sentinel
//   nw = (t ? -0.07 : -0.28) * log(sel+1e-4)                    (nbr num, -0.35*k folded)
__global__ __launch_bounds__(256) void scloss_main(
    const float* __restrict__ cmap, const int* __restrict__ tgt,
    float* __restrict__ out)
{
    __shared__ float4 pack[LROWS * LCOLS];

    const int tilesPerRow = IMG_W / TILE;                 // 16
    const int tilesPerImg = (IMG_H / TILE) * tilesPerRow; // 256
    int blk = blockIdx.x;
    int b   = blk / tilesPerImg;
    int ti  = blk % tilesPerImg;
    int tr  = (ti / tilesPerRow) * TILE;
    int tc  = (ti % tilesPerRow) * TILE;

    const float* cimg = cmap + (size_t)b * (IMG_H * IMG_W);
    const int*   timg = tgt  + (size_t)b * (IMG_H * IMG_W);

    // Stage rows tr..tr+33, cols tc-2..tc+33.
    for (int idx = threadIdx.x; idx < LROWS * LCOLS; idx += 256) {
        int lr = idx / LCOLS, lc = idx - lr * LCOLS;
        int gr = tr + lr, gc = tc + lc - 2;
        float4 v = make_float4(0.0f, 0.0f, 0.0f, 0.0f);
        if (gr < IMG_H && (unsigned)gc < (unsigned)IMG_W) {
            float x = cimg[gr * IMG_W + gc];
            bool  t = timg[gr * IMG_W + gc] != 0;
            float s   = frcp(1.0f + fexp2(x * -LOG2E));
            float sel = t ? s : (1.0f - s);
            float L   = LN2 * flog2(sel + 1e-4f);
            float e   = fexp2(s * -LOG2E);
            v = make_float4(s,
                            (t ? -0.6f : -1.4f) * L,
                            t ? -e : e,
                            (t ? -0.07f : -0.28f) * L);
        }
        pack[idx] = v;
    }
    __syncthreads();

    int j  = threadIdx.x & 31;
    int i0 = threadIdx.x >> 5;      // 0..7 -> owner rows 4*i0..4*i0+3
    float acc = 0.0f;

// One edge, named-scalar outputs only (compile-time offsets -> pure registers).
#define EDGE(VBX, Dd, Nn, WSK, MK) do {                                   \
        float4 vb  = (VBX);                                               \
        bool  tb   = vb.z < 0.0f;                                         \
        bool  qpos = (ta == tb);           /* both targets equal */       \
        bool  qnz  = vb.z != 0.0f;         /* neighbor in bounds */       \
        float ppp  = __builtin_fmaf(sa, vb.x, 1e-4f);                     \
        float ompp = __builtin_fmaf(-sa, vb.x, 1.0001f);                  \
        float argc = (qpos && ta) ? ppp : ompp;                           \
        float lg   = flog2(argc);                                         \
        float E    = fexp2(__builtin_fmaf(ppp, -LOG2E, 1e-4f * LOG2E));   \
        float een  = ta ? vb.z : epa;      /* e' of the t=0 endpoint */   \
        float ee   = qpos ? E : een;                                      \
        Dd         = __builtin_fmaf(-LN2, lg, ee);                        \
        float nm   = qpos ? __builtin_fmaf(WSK, vb.y, MK) : (nwa + vb.w); \
        Nn         = qnz ? nm : 0.0f;                                     \
    } while (0)

// 4 divisions with one reciprocal.
#define COMBINE do {                                                      \
        float d01 = D0 * D1, d23 = D2 * D3;                               \
        float R   = frcp(d01 * d23);                                      \
        float n01 = __builtin_fmaf(N1, D0, N0 * D1);                      \
        float n23 = __builtin_fmaf(N3, D2, N2 * D3);                      \
        acc = __builtin_fmaf(__builtin_fmaf(n23, d01, n01 * d23), R, acc);\
    } while (0)

// One pixel: 8 edges.  S1X/S2X = the (row+1)/(row+2) packs, register-reused
// where they are the thread's own pixels.
#define PIXEL(VA, S1X, S2X, base) do {                                    \
        float4 va_ = (VA);                                                \
        bool  ta  = va_.z < 0.0f;                                         \
        float sa  = va_.x, nwa = va_.w, epa = va_.z;                      \
        float mwa = va_.y, hmw = 0.5f * va_.y;                            \
        float D0, D1, D2, D3, N0, N1, N2, N3;                             \
        EDGE(base[1],           D0, N0, 1.0f, mwa);   /* E  K1 */         \
        EDGE(base[LCOLS + 1],   D1, N1, 1.0f, mwa);   /* SE K1 */         \
        EDGE(S1X,               D2, N2, 1.0f, mwa);   /* S  K1 */         \
        EDGE(base[LCOLS - 1],   D3, N3, 1.0f, mwa);   /* SW K1 */         \
        COMBINE;                                                          \
        EDGE(base[2],           D0, N0, 0.5f, hmw);   /* E  K2 */         \
        EDGE(base[2*LCOLS + 2], D1, N1, 0.5f, hmw);   /* SE K2 */         \
        EDGE(S2X,               D2, N2, 0.5f, hmw);   /* S  K2 */         \
        EDGE(base[2*LCOLS - 2], D3, N3, 0.5f, hmw);   /* SW K2 */         \
        COMBINE;                                                          \
    } while (0)

    {
        const float4* b0 = &pack[(i0 * 4) * LCOLS + (j + 2)];
        const float4* b1 = b0 + LCOLS;
        const float4* b2 = b1 + LCOLS;
        const float4* b3 = b2 + LCOLS;
        float4 va0 = b0[0], va1 = b1[0], va2 = b2[0], va3 = b3[0];
        PIXEL(va0, va1, va2,            b0);
        PIXEL(va1, va2, va3,            b1);
        PIXEL(va2, va3, b2[2 * LCOLS],  b2);
        PIXEL(va3, b3[LCOLS], b3[2 * LCOLS], b3);
    }
#undef PIXEL
#undef COMBINE
#undef EDGE

    // Block reduction: wave64 shuffle then cross-wave via LDS.
    #pragma unroll
    for (int o = 32; o > 0; o >>= 1) acc += __shfl_down(acc, o, 64);
    __shared__ float wsum[4];
    int lane = threadIdx.x & 63, wid = threadIdx.x >> 6;
    if (lane == 0) wsum[wid] = acc;
    __syncthreads();
    if (threadIdx.x == 0) {
        float bs = (wsum[0] + wsum[1] + wsum[2] + wsum[3]) * INV_N_MEAN;
        // Relaxed, non-returning, device-scope-coherent HW f32 atomic.
        // NO release fence / acq-rel RMW (that was the R3/R5 L2-writeback trap).
        atomicAdd(out, bs);
    }
}

extern "C" void kernel_launch(void* const* d_in, const int* in_sizes, int n_in,
                              void* d_out, int out_size, void* d_ws, size_t ws_size,
                              hipStream_t stream) {
    const float* cmap = (const float*)d_in[0];
    const int*   tgt  = (const int*)d_in[1];
    float* out = (float*)d_out;

    hipMemsetAsync(out, 0, sizeof(float), stream);   // accumulator = 0 each call
    scloss_main<<<NBLK, 256, 0, stream>>>(cmap, tgt, out);
}

// Round 8
// 24.413 us; speedup vs baseline: 1.8158x; 1.8158x over previous
//
#include <hip/hip_runtime.h>

#define IMG_H 512
#define IMG_W 512
#define NB    8
#define TILE  32
#define LROWS 34            // owner rows 0..31 + 2 halo rows below
#define LCOLS 36            // owner col j -> lds col j+2 (halo +-2)
#define NBLK  (NB * (IMG_H / TILE) * (IMG_W / TILE))   // 2048
#define N_MEAN 16777216.0   // B * 8 dirs * H * W
#define LOG2E 1.44269504f
#define LN2   0.69314718f

typedef __attribute__((ext_vector_type(2))) float f32x2;

__device__ __forceinline__ float frcp(float x){ return __builtin_amdgcn_rcpf(x); }
__device__ __forceinline__ float fexp2(float x){ return __builtin_amdgcn_exp2f(x); }
__device__ __forceinline__ float flog2(float x){ return __builtin_amdgcn_logf(x); }

// Per-pixel pack {s, mw, e', nw}:
//   s  = sigmoid(c_map)
//   mw = (t ? -0.6 : -1.4) * log(sel+1e-4), sel = t ? s : 1-s   (eq-pair num, K=1 weight)
//   e' = (t ? -1 : +1) * exp(-s);  e' == 0  => OOB sentinel
//   nw = (t ? -0.07 : -0.28) * log(sel+1e-4)                    (nbr num, -0.35*k folded)
__global__ __launch_bounds__(256, 8) void scloss_main(
    const float* __restrict__ cmap, const int* __restrict__ tgt,
    float* __restrict__ partials)
{
    __shared__ float4 pack[LROWS * LCOLS];

    const int tilesPerRow = IMG_W / TILE;                 // 16
    const int tilesPerImg = (IMG_H / TILE) * tilesPerRow; // 256
    int blk = blockIdx.x;
    int b   = blk / tilesPerImg;
    int ti  = blk % tilesPerImg;
    int tr  = (ti / tilesPerRow) * TILE;
    int tc  = (ti % tilesPerRow) * TILE;

    const float* cimg = cmap + (size_t)b * (IMG_H * IMG_W);
    const int*   timg = tgt  + (size_t)b * (IMG_H * IMG_W);

    // Stage rows tr..tr+33, cols tc-2..tc+33.
    for (int idx = threadIdx.x; idx < LROWS * LCOLS; idx += 256) {
        int lr = idx / LCOLS, lc = idx - lr * LCOLS;
        int gr = tr + lr, gc = tc + lc - 2;
        float4 v = make_float4(0.0f, 0.0f, 0.0f, 0.0f);
        if (gr < IMG_H && (unsigned)gc < (unsigned)IMG_W) {
            float x = cimg[gr * IMG_W + gc];
            bool  t = timg[gr * IMG_W + gc] != 0;
            float s   = frcp(1.0f + fexp2(x * -LOG2E));
            float sel = t ? s : (1.0f - s);
            float L   = LN2 * flog2(sel + 1e-4f);
            float e   = fexp2(s * -LOG2E);
            v = make_float4(s,
                            (t ? -0.6f : -1.4f) * L,
                            t ? -e : e,
                            (t ? -0.07f : -0.28f) * L);
        }
        pack[idx] = v;
    }
    __syncthreads();

    int j  = threadIdx.x & 31;
    int i0 = threadIdx.x >> 5;      // 0..7 -> owner rows 4*i0..4*i0+3

    // Uniform packed constants.
    const f32x2 C1E4   = {1e-4f, 1e-4f};
    const f32x2 C10001 = {1.0001f, 1.0001f};
    const f32x2 MLOG2E = {-LOG2E, -LOG2E};
    const f32x2 CEC    = {1e-4f * LOG2E, 1e-4f * LOG2E};
    const f32x2 MLN2V  = {-LN2, -LN2};
    const f32x2 WSK2   = {1.0f, 0.5f};      // K=1, K=2 eq-weight scale

    f32x2 acc2 = {0.0f, 0.0f};

// One direction, both K's packed: component 0 = K1 edge, component 1 = K2 edge.
// All fma/mul/max are f32x2 (-> v_pk_* on CDNA); selects & exp/log scalar.
#define EDGEPAIR(VB1, VB2, Dd, Nn) do {                                   \
        float4 vb1 = (VB1), vb2 = (VB2);                                  \
        f32x2 vx = {vb1.x, vb2.x}, vy = {vb1.y, vb2.y};                   \
        f32x2 vz = {vb1.z, vb2.z}, vw = {vb1.w, vb2.w};                   \
        bool qp0 = (ta == (vb1.z < 0.0f));                                \
        bool qp1 = (ta == (vb2.z < 0.0f));                                \
        f32x2 ppp  = __builtin_elementwise_fma(sa2, vx, C1E4);            \
        f32x2 ompp = __builtin_elementwise_fma(msa2, vx, C10001);         \
        f32x2 argc;                                                       \
        argc[0] = (qp0 && ta) ? ppp[0] : ompp[0];                         \
        argc[1] = (qp1 && ta) ? ppp[1] : ompp[1];                         \
        f32x2 lg = {flog2(argc[0]), flog2(argc[1])};                      \
        f32x2 ein = __builtin_elementwise_fma(ppp, MLOG2E, CEC);          \
        f32x2 een = __builtin_elementwise_max(epa2, vz);                  \
        f32x2 ee;                                                         \
        ee[0] = qp0 ? fexp2(ein[0]) : een[0];                             \
        ee[1] = qp1 ? fexp2(ein[1]) : een[1];                             \
        Dd = __builtin_elementwise_fma(MLN2V, lg, ee);                    \
        f32x2 nume = __builtin_elementwise_fma(WSK2, vy, mk2);            \
        f32x2 numn = nwa2 + vw;                                           \
        f32x2 nm;                                                         \
        nm[0] = qp0 ? nume[0] : numn[0];                                  \
        nm[1] = qp1 ? nume[1] : numn[1];                                  \
        Nn[0] = (vb1.z != 0.0f) ? nm[0] : 0.0f;                           \
        Nn[1] = (vb2.z != 0.0f) ? nm[1] : 0.0f;                           \
    } while (0)

// One pixel: 4 direction-pairs, then both K-group combines packed
// (component k = the 4-edge one-reciprocal combine of K-group k).
#define PIXEL(VA, S1X, S2X, base) do {                                    \
        float4 va_ = (VA);                                                \
        bool  ta  = va_.z < 0.0f;                                         \
        float sa  = va_.x;                                                \
        f32x2 sa2  = {sa, sa}, msa2 = {-sa, -sa};                         \
        f32x2 epa2 = {va_.z, va_.z}, nwa2 = {va_.w, va_.w};               \
        f32x2 mk2  = {va_.y, 0.5f * va_.y};                               \
        f32x2 DE, NE, DSE, NSE, DS, NS, DSW, NSW;                         \
        EDGEPAIR(base[1],         base[2],             DE,  NE);          \
        EDGEPAIR(base[LCOLS + 1], base[2*LCOLS + 2],   DSE, NSE);         \
        EDGEPAIR(S1X,             S2X,                 DS,  NS);          \
        EDGEPAIR(base[LCOLS - 1], base[2*LCOLS - 2],   DSW, NSW);         \
        f32x2 d01 = DE * DSE, d23 = DS * DSW;                             \
        f32x2 pr  = d01 * d23;                                            \
        f32x2 R   = {frcp(pr[0]), frcp(pr[1])};                           \
        f32x2 n01 = __builtin_elementwise_fma(NSE, DE, NE * DSE);         \
        f32x2 n23 = __builtin_elementwise_fma(NSW, DS, NS * DSW);         \
        f32x2 nn  = __builtin_elementwise_fma(n23, d01, n01 * d23);       \
        acc2 = __builtin_elementwise_fma(nn, R, acc2);                    \
    } while (0)

    {
        const float4* b0 = &pack[(i0 * 4) * LCOLS + (j + 2)];
        const float4* b1 = b0 + LCOLS;
        const float4* b2 = b1 + LCOLS;
        const float4* b3 = b2 + LCOLS;
        float4 va0 = b0[0], va1 = b1[0], va2 = b2[0], va3 = b3[0];
        PIXEL(va0, va1, va2,                  b0);
        PIXEL(va1, va2, va3,                  b1);
        PIXEL(va2, va3, b2[2 * LCOLS],        b2);
        PIXEL(va3, b3[LCOLS], b3[2 * LCOLS],  b3);
    }
#undef PIXEL
#undef EDGEPAIR

    float acc = acc2[0] + acc2[1];

    // Block reduction: wave64 shuffle then cross-wave via LDS.
    #pragma unroll
    for (int o = 32; o > 0; o >>= 1) acc += __shfl_down(acc, o, 64);
    __shared__ float wsum[4];
    int lane = threadIdx.x & 63, wid = threadIdx.x >> 6;
    if (lane == 0) wsum[wid] = acc;
    __syncthreads();
    if (threadIdx.x == 0)
        partials[blockIdx.x] = wsum[0] + wsum[1] + wsum[2] + wsum[3];
}

__global__ __launch_bounds__(256) void scloss_final(
    const float* __restrict__ partials, int n, float* __restrict__ out)
{
    double a = 0.0;
    for (int i = threadIdx.x; i < n; i += 256) a += (double)partials[i];
    __shared__ double sd[256];
    sd[threadIdx.x] = a;
    __syncthreads();
    for (int s = 128; s > 0; s >>= 1) {
        if (threadIdx.x < s) sd[threadIdx.x] += sd[threadIdx.x + s];
        __syncthreads();
    }
    if (threadIdx.x == 0) out[0] = (float)(sd[0] / N_MEAN);
}

extern "C" void kernel_launch(void* const* d_in, const int* in_sizes, int n_in,
                              void* d_out, int out_size, void* d_ws, size_t ws_size,
                              hipStream_t stream) {
    const float* cmap = (const float*)d_in[0];
    const int*   tgt  = (const int*)d_in[1];
    float* out      = (float*)d_out;
    float* partials = (float*)d_ws;

    scloss_main<<<NBLK, 256, 0, stream>>>(cmap, tgt, partials);
    scloss_final<<<1, 256, 0, stream>>>(partials, NBLK, out);
}

// Round 9
// 24.399 us; speedup vs baseline: 1.8168x; 1.0006x over previous
//
#include <hip/hip_runtime.h>

#define IMG_H 512
#define IMG_W 512
#define NB    8
#define TILE  32
#define LROWS 34            // owner rows 0..31 + 2 halo rows below
#define LCOLS 36            // owner col j -> lds col j+2 (halo +-2)
#define NBLK  (NB * (IMG_H / TILE) * (IMG_W / TILE))   // 2048
#define N_MEAN 16777216.0   // B * 8 dirs * H * W
#define LOG2E 1.44269504f
#define LN2   0.69314718f

__device__ __forceinline__ float frcp(float x){ return __builtin_amdgcn_rcpf(x); }
__device__ __forceinline__ float fexp2(float x){ return __builtin_amdgcn_exp2f(x); }
__device__ __forceinline__ float flog2(float x){ return __builtin_amdgcn_logf(x); }

// Per-pixel pack {s, mw, e', nw}:
//   s  = sigmoid(c_map)
//   mw = (t ? -0.6 : -1.4) * log(sel+1e-4), sel = t ? s : 1-s   (eq-pair num, K=1 weight)
//   e' = (t ? -1 : +1) * exp(-s);  e' == 0  => OOB sentinel
//   nw = (t ? -0.07 : -0.28) * log(sel+1e-4)                    (nbr num, -0.35*k folded)
__global__ __launch_bounds__(256, 8) void scloss_main(
    const float* __restrict__ cmap, const int* __restrict__ tgt,
    float* __restrict__ partials)
{
    __shared__ float4 pack[LROWS * LCOLS];

    const int tilesPerRow = IMG_W / TILE;                 // 16
    const int tilesPerImg = (IMG_H / TILE) * tilesPerRow; // 256
    int blk = blockIdx.x;
    int b   = blk / tilesPerImg;
    int ti  = blk % tilesPerImg;
    int tr  = (ti / tilesPerRow) * TILE;
    int tc  = (ti % tilesPerRow) * TILE;

    const float* cimg = cmap + (size_t)b * (IMG_H * IMG_W);
    const int*   timg = tgt  + (size_t)b * (IMG_H * IMG_W);

    // Stage rows tr..tr+33, cols tc-2..tc+33.
    for (int idx = threadIdx.x; idx < LROWS * LCOLS; idx += 256) {
        int lr = idx / LCOLS, lc = idx - lr * LCOLS;
        int gr = tr + lr, gc = tc + lc - 2;
        float4 v = make_float4(0.0f, 0.0f, 0.0f, 0.0f);
        if (gr < IMG_H && (unsigned)gc < (unsigned)IMG_W) {
            float x = cimg[gr * IMG_W + gc];
            bool  t = timg[gr * IMG_W + gc] != 0;
            float s   = frcp(1.0f + fexp2(x * -LOG2E));
            float sel = t ? s : (1.0f - s);
            float L   = LN2 * flog2(sel + 1e-4f);
            float e   = fexp2(s * -LOG2E);
            v = make_float4(s,
                            (t ? -0.6f : -1.4f) * L,
                            t ? -e : e,
                            (t ? -0.07f : -0.28f) * L);
        }
        pack[idx] = v;
    }
    __syncthreads();

    int j  = threadIdx.x & 31;
    int i0 = threadIdx.x >> 5;      // 0..7 -> owner rows 4*i0..4*i0+3
    float acc = 0.0f;

// One edge on a PRE-LOADED neighbor float4 (vb), named-scalar outputs only.
#define EDGE(VB, Dd, Nn, WSK, MK) do {                                    \
        float4 vb  = (VB);                                                \
        bool  tb   = vb.z < 0.0f;                                         \
        bool  qpos = (ta == tb);           /* both targets equal */       \
        bool  qnz  = vb.z != 0.0f;         /* neighbor in bounds */       \
        float ppp  = __builtin_fmaf(sa, vb.x, 1e-4f);                     \
        float ompp = __builtin_fmaf(-sa, vb.x, 1.0001f);                  \
        float argc = (qpos && ta) ? ppp : ompp;                           \
        float lg   = flog2(argc);                                         \
        float E    = fexp2(__builtin_fmaf(ppp, -LOG2E, 1e-4f * LOG2E));   \
        float een  = ta ? vb.z : epa;      /* e' of the t=0 endpoint */   \
        float ee   = qpos ? E : een;                                      \
        Dd         = __builtin_fmaf(-LN2, lg, ee);                        \
        float nm   = qpos ? __builtin_fmaf(WSK, vb.y, MK) : (nwa + vb.w); \
        Nn         = qnz ? nm : 0.0f;                                     \
    } while (0)

// 4 divisions with one reciprocal.
#define COMBINE do {                                                      \
        float d01 = D0 * D1, d23 = D2 * D3;                               \
        float R   = frcp(d01 * d23);                                      \
        float n01 = __builtin_fmaf(N1, D0, N0 * D1);                      \
        float n23 = __builtin_fmaf(N3, D2, N2 * D3);                      \
        acc = __builtin_fmaf(__builtin_fmaf(n23, d01, n01 * d23), R, acc);\
    } while (0)

// One pixel: HOIST all neighbor loads into named registers first (8 b128s
// in flight -> LDS latency covered by issue distance), THEN the math.
#define PIXEL(VA, S1X, S2X, base) do {                                    \
        float4 va_  = (VA);                                               \
        float4 nE1  = base[1],         nE2  = base[2];                    \
        float4 nSE1 = base[LCOLS + 1], nSE2 = base[2*LCOLS + 2];          \
        float4 nSW1 = base[LCOLS - 1], nSW2 = base[2*LCOLS - 2];          \
        float4 nS1  = (S1X),           nS2  = (S2X);                      \
        bool  ta  = va_.z < 0.0f;                                         \
        float sa  = va_.x, nwa = va_.w, epa = va_.z;                      \
        float mwa = va_.y, hmw = 0.5f * va_.y;                            \
        float D0, D1, D2, D3, N0, N1, N2, N3;                             \
        EDGE(nE1,  D0, N0, 1.0f, mwa);   /* E  K1 */                      \
        EDGE(nSE1, D1, N1, 1.0f, mwa);   /* SE K1 */                      \
        EDGE(nS1,  D2, N2, 1.0f, mwa);   /* S  K1 */                      \
        EDGE(nSW1, D3, N3, 1.0f, mwa);   /* SW K1 */                      \
        COMBINE;                                                          \
        EDGE(nE2,  D0, N0, 0.5f, hmw);   /* E  K2 */                      \
        EDGE(nSE2, D1, N1, 0.5f, hmw);   /* SE K2 */                      \
        EDGE(nS2,  D2, N2, 0.5f, hmw);   /* S  K2 */                      \
        EDGE(nSW2, D3, N3, 0.5f, hmw);   /* SW K2 */                      \
        COMBINE;                                                          \
    } while (0)

    {
        const float4* b0 = &pack[(i0 * 4) * LCOLS + (j + 2)];
        const float4* b1 = b0 + LCOLS;
        const float4* b2 = b1 + LCOLS;
        const float4* b3 = b2 + LCOLS;
        float4 va0 = b0[0], va1 = b1[0], va2 = b2[0], va3 = b3[0];
        PIXEL(va0, va1, va2,                  b0);
        PIXEL(va1, va2, va3,                  b1);
        PIXEL(va2, va3, b2[2 * LCOLS],        b2);
        PIXEL(va3, b3[LCOLS], b3[2 * LCOLS],  b3);
    }
#undef PIXEL
#undef COMBINE
#undef EDGE

    // Block reduction: wave64 shuffle then cross-wave via LDS.
    #pragma unroll
    for (int o = 32; o > 0; o >>= 1) acc += __shfl_down(acc, o, 64);
    __shared__ float wsum[4];
    int lane = threadIdx.x & 63, wid = threadIdx.x >> 6;
    if (lane == 0) wsum[wid] = acc;
    __syncthreads();
    if (threadIdx.x == 0)
        partials[blockIdx.x] = wsum[0] + wsum[1] + wsum[2] + wsum[3];
}

__global__ __launch_bounds__(256) void scloss_final(
    const float* __restrict__ partials, int n, float* __restrict__ out)
{
    double a = 0.0;
    for (int i = threadIdx.x; i < n; i += 256) a += (double)partials[i];
    __shared__ double sd[256];
    sd[threadIdx.x] = a;
    __syncthreads();
    for (int s = 128; s > 0; s >>= 1) {
        if (threadIdx.x < s) sd[threadIdx.x] += sd[threadIdx.x + s];
        __syncthreads();
    }
    if (threadIdx.x == 0) out[0] = (float)(sd[0] / N_MEAN);
}

extern "C" void kernel_launch(void* const* d_in, const int* in_sizes, int n_in,
                              void* d_out, int out_size, void* d_ws, size_t ws_size,
                              hipStream_t stream) {
    const float* cmap = (const float*)d_in[0];
    const int*   tgt  = (const int*)d_in[1];
    float* out      = (float*)d_out;
    float* partials = (float*)d_ws;

    scloss_main<<<NBLK, 256, 0, stream>>>(cmap, tgt, partials);
    scloss_final<<<1, 256, 0, stream>>>(partials, NBLK, out);
}